// Round 7
// baseline (485.469 us; speedup 1.0000x reference)
//
#include <hip/hip_runtime.h>

using half8   = __attribute__((ext_vector_type(8))) _Float16;
using half4   = __attribute__((ext_vector_type(4))) _Float16;
using floatx4 = __attribute__((ext_vector_type(4))) float;

namespace {
constexpr int S = 196, D = 512, C = 1006, Cpad = 1024;
constexpr int CB = 16;      // block c-tile
constexpr int EBLK = 512;   // FULL e per block -> tanh duplication eliminated
constexpr int BK = 64;      // k-chunk (8 chunks, 2 MFMA k-steps each)
constexpr int TPB = 512;    // 8 waves; state/wave: 32 AGPR + 32 sum VGPR -> 2 blocks/CU
constexpr int SCH = 4;      // s-chunks of 49 -> grid 512 = 2 blocks/CU
constexpr int RS = 64;      // LDS row stride (halfs); banks via XOR swizzle
constexpr float KTANH = 2.885390082f;    // 2/ln2 folded into img staging
constexpr float INVK  = 0.34657359028f;  // ln2/2 to recover raw img
constexpr float LOG2E = 1.44269504f;     // folded into W at prep: acc = log2e*feat

// ws layout (bytes) — NEED = 34,078,720 B; r6 ran the slice path at exactly this size.
constexpr size_t W16_BYTES = (size_t)D * D * 2;               // 512 KB swizzled W
constexpr size_t LA_OFF    = W16_BYTES;
constexpr size_t SLICE_ELEMS = (size_t)2 * Cpad * D;
constexpr size_t SL_BYTES  = (size_t)SCH * SLICE_ELEMS * 4;   // 16 MB per set
constexpr size_t SLICE_NEED = LA_OFF + 2 * SL_BYTES;
constexpr size_t L_BYTES   = SLICE_ELEMS * 4;

// swizzled LDS offset (halfs): row stride 64, 16B-seg XOR'd by row&7
// (conflict-free on b128 frag reads — SQ_LDS_BANK_CONFLICT==0 in r3/r4)
__device__ __forceinline__ int sw_off(int row, int seg) {
    return row * RS + ((seg ^ (row & 7)) << 3);
}

__device__ __forceinline__ void gload16(const _Float16* g, _Float16* l) {
    // async global->LDS, 16B/lane; LDS dest = wave-uniform base + lane*16
    __builtin_amdgcn_global_load_lds(
        (const __attribute__((address_space(1))) unsigned int*)g,
        (__attribute__((address_space(3))) unsigned int*)l, 16, 0, 0);
}

__device__ __forceinline__ _Float16 tanh_ps(float y) {
    // y = (2/ln2)*x; tanh(x) = 1 - 2/(exp2(y)+1); saturates correctly
    float e = __builtin_amdgcn_exp2f(y);
    return (_Float16)(1.0f - 2.0f * __builtin_amdgcn_rcpf(e + 1.0f));
}

// Pre-swizzle fc3_w*log2e into the exact per-chunk LDS image
// (8 chunks of 512 rows x 8 16B-segs, seg XOR row&7) — same image the kernel DMAs.
__global__ void prep_w16sw(const float* __restrict__ fw, _Float16* __restrict__ W16sw) {
    int id = blockIdx.x * blockDim.x + threadIdx.x;    // 32768 segs
    int kki = id >> 12;
    int r   = (id >> 3) & 511;
    int j   = id & 7;
    const float* src = fw + (size_t)r * D + kki * BK + j * 8;
    floatx4 v0 = *(const floatx4*)src;
    floatx4 v1 = *(const floatx4*)(src + 4);
    half8 h;
    h[0] = (_Float16)(v0[0] * LOG2E); h[1] = (_Float16)(v0[1] * LOG2E);
    h[2] = (_Float16)(v0[2] * LOG2E); h[3] = (_Float16)(v0[3] * LOG2E);
    h[4] = (_Float16)(v1[0] * LOG2E); h[5] = (_Float16)(v1[1] * LOG2E);
    h[6] = (_Float16)(v1[2] * LOG2E); h[7] = (_Float16)(v1[3] * LOG2E);
    W16sw[((size_t)kki << 15) + r * RS + ((j ^ (r & 7)) << 3)] = h[0];
    *(half8*)&W16sw[((size_t)kki << 15) + r * RS + ((j ^ (r & 7)) << 3)] = h;
}

__global__ __launch_bounds__(TPB, 2) void semdec_mfma(
    const float* __restrict__ img, const float* __restrict__ word,
    const _Float16* __restrict__ W16sw,
    float* __restrict__ lbase, float* __restrict__ abase, int use_slice)
{
    __shared__ __align__(16) _Float16 Wc[EBLK * RS];   // 64 KB (512 e x 64 k)
    __shared__ __align__(16) _Float16 Tc[2 * CB * RS]; // 4 KB (2 s x 16 c x 64 k)
    __shared__ __align__(16) float imgS[2][D];         // 4 KB, pre-scaled by 2/ln2
    // total 72 KB -> 2 blocks/CU; regs/wave ~115 -> 4 waves/SIMD

    const int ct = blockIdx.x;           // 0..63
    const int b  = blockIdx.y;           // 0..1
    const int sc = blockIdx.z;           // 0..3

    const int tid  = threadIdx.x;
    const int lane = tid & 63;
    const int wv   = tid >> 6;           // wave 0..7 = 64-wide e-slot
    const int l15  = lane & 15;
    const int quad = lane >> 4;

    const int c0 = ct * CB;

    // T-stage mapping: each thread computes one half4 (4 tanh) per chunk
    const int siT  = tid >> 8;           // 0..1 (wave-uniform)
    const int ciT  = (tid >> 4) & 15;    // 0..15
    const int segT = (tid >> 1) & 7;     // 0..7
    const int hsT  = tid & 1;            // which half of the 16B seg
    int cgT = c0 + ciT; if (cgT > C - 1) cgT = C - 1;   // clamp pad rows
    const float* wordRowT = word + (size_t)cgT * D;

    floatx4 lacc[4], aacc[4];            // 32 VGPR softmax sums
    #pragma unroll
    for (int ej = 0; ej < 4; ++ej) {
        lacc[ej] = (floatx4){0.f, 0.f, 0.f, 0.f};
        aacc[ej] = (floatx4){0.f, 0.f, 0.f, 0.f};
    }

    const float* imgB = img + (size_t)b * S * D;
    const int s_base = sc * 49;

    for (int pr = 0; pr < 25; ++pr) {
        const int s0 = s_base + pr * 2;
        const int slim = (pr == 24) ? 1 : 2;   // last pass covers 1 s

        __syncthreads();  // prior pass: imgS readers + last-chunk MFMA done
        if (tid < 256) {
            int si = tid >> 7, pos = (tid & 127) << 2;
            int srow = s0 + si; if (srow > S - 1) srow = S - 1;   // tail clamp
            floatx4 v = *(const floatx4*)&imgB[(size_t)srow * D + pos];
            floatx4 sv = {v[0] * KTANH, v[1] * KTANH, v[2] * KTANH, v[3] * KTANH};
            *(floatx4*)&imgS[si][pos] = sv;
        }

        floatx4 acc[2][4];   // [si][ej] 32 AGPR
        #pragma unroll
        for (int si = 0; si < 2; ++si)
            #pragma unroll
            for (int ej = 0; ej < 4; ++ej)
                acc[si][ej] = (floatx4){0.f, 0.f, 0.f, 0.f};

        for (int kk = 0; kk < D; kk += BK) {
            const int kki = kk >> 6;
            __syncthreads();  // prev chunk frag readers done / imgS staged (kk=0)
            // --- W chunk: async DMA of pre-swizzled image, 64 KB (8 KB per wave)
            {
                const _Float16* wg = W16sw + ((size_t)kki << 15);
                #pragma unroll
                for (int it = 0; it < 8; ++it) {
                    int o = ((wv * 8 + it) << 9) + (lane << 3);
                    gload16(wg + o, &Wc[o]);
                }
            }
            // --- T chunk: 2s x 16c x 64k = 2048 elems, one half4 per thread
            {
                const float* wp = wordRowT + kk + segT * 8 + hsT * 4;
                floatx4 w = *(const floatx4*)wp;
                const float* ip = &imgS[siT][kk + segT * 8 + hsT * 4];
                floatx4 iv = *(const floatx4*)ip;
                half4 t;
                t[0] = tanh_ps(iv[0] * w[0]);
                t[1] = tanh_ps(iv[1] * w[1]);
                t[2] = tanh_ps(iv[2] * w[2]);
                t[3] = tanh_ps(iv[3] * w[3]);
                *(half4*)&Tc[sw_off(siT * CB + ciT, segT) + hsT * 4] = t;
            }
            __syncthreads();  // drains vmcnt (async W) + lgkm (T writes)
            // --- MFMA: 2 k-steps of 32; 8 MFMA per k-step
            #pragma unroll
            for (int k2 = 0; k2 < 2; ++k2) {
                const int jb = (k2 << 2) + quad;
                half8 af[2], bf[4];
                #pragma unroll
                for (int si = 0; si < 2; ++si)
                    af[si] = *(const half8*)&Tc[sw_off(si * CB + l15, jb)];
                #pragma unroll
                for (int ej = 0; ej < 4; ++ej)
                    bf[ej] = *(const half8*)&Wc[sw_off(wv * 64 + ej * 16 + l15, jb)];
                #pragma unroll
                for (int si = 0; si < 2; ++si)
                    #pragma unroll
                    for (int ej = 0; ej < 4; ++ej)
                        acc[si][ej] = __builtin_amdgcn_mfma_f32_16x16x32_f16(
                            af[si], bf[ej], acc[si][ej], 0, 0, 0);
            }
        }
        // --- online softmax accumulate; acc = log2e*feat, so exp2(acc) = exp(feat)
        #pragma unroll
        for (int si = 0; si < 2; ++si) {
            if (si >= slim) break;
            #pragma unroll
            for (int ej = 0; ej < 4; ++ej) {
                float ie = imgS[si][wv * 64 + ej * 16 + l15] * INVK;
                #pragma unroll
                for (int r = 0; r < 4; ++r) {
                    float ev = __builtin_amdgcn_exp2f(acc[si][ej][r]);
                    lacc[ej][r] += ev;
                    aacc[ej][r] += ie * ev;
                }
            }
        }
    }

    // --- writeout (C/D layout: col=lane&15 -> e, row=quad*4+r -> c)
    if (use_slice) {
        float* lsl = lbase + (size_t)sc * SLICE_ELEMS;
        float* asl = abase + (size_t)sc * SLICE_ELEMS;
        #pragma unroll
        for (int r = 0; r < 4; ++r) {
            int cg = c0 + quad * 4 + r;
            #pragma unroll
            for (int ej = 0; ej < 4; ++ej) {
                int eg = wv * 64 + ej * 16 + l15;
                size_t o = ((size_t)b * Cpad + cg) * D + eg;
                lsl[o] = lacc[ej][r];
                asl[o] = aacc[ej][r];
            }
        }
    } else {
        #pragma unroll
        for (int r = 0; r < 4; ++r) {
            int cg = c0 + quad * 4 + r;
            #pragma unroll
            for (int ej = 0; ej < 4; ++ej) {
                int eg = wv * 64 + ej * 16 + l15;
                atomicAdd(&lbase[((size_t)b * Cpad + cg) * D + eg], lacc[ej][r]);
                if (cg < C)
                    atomicAdd(&abase[((size_t)b * C + cg) * D + eg], aacc[ej][r]);
            }
        }
    }
}

__global__ void finalize_k(const float* __restrict__ lbase, const float* __restrict__ abase,
                           float* __restrict__ out, int use_slice) {
    int o = blockIdx.x * blockDim.x + threadIdx.x;
    if (o >= 2 * C * D) return;
    int b = o / (C * D);
    int rem = o - b * (C * D);
    int c = rem >> 9;
    int e = rem & (D - 1);
    size_t p = ((size_t)b * Cpad + c) * D + e;
    if (use_slice) {
        float l = 0.f, a = 0.f;
        #pragma unroll
        for (int scn = 0; scn < SCH; ++scn) {
            l += lbase[(size_t)scn * SLICE_ELEMS + p];
            a += abase[(size_t)scn * SLICE_ELEMS + p];
        }
        out[o] = a / l;
    } else {
        out[o] = out[o] / lbase[p];
    }
}

} // namespace

extern "C" void kernel_launch(void* const* d_in, const int* in_sizes, int n_in,
                              void* d_out, int out_size, void* d_ws, size_t ws_size,
                              hipStream_t stream) {
    const float* img  = (const float*)d_in[0];
    const float* word = (const float*)d_in[1];
    const float* fw   = (const float*)d_in[2];
    // d_in[3] = fc3_b: constant over softmax axis s -> cancels exactly.
    float* out = (float*)d_out;
    char* ws = (char*)d_ws;

    _Float16* W16sw = (_Float16*)ws;
    const int use_slice = (ws_size >= SLICE_NEED) ? 1 : 0;

    hipLaunchKernelGGL(prep_w16sw, dim3(128), dim3(256), 0, stream, fw, W16sw);

    float *lbase, *abase;
    if (use_slice) {
        lbase = (float*)(ws + LA_OFF);
        abase = (float*)(ws + LA_OFF + SL_BYTES);
    } else {
        lbase = (float*)(ws + LA_OFF);
        abase = out;
        hipMemsetAsync(lbase, 0, L_BYTES, stream);
        hipMemsetAsync(out, 0, (size_t)2 * C * D * 4, stream);
    }

    hipLaunchKernelGGL(semdec_mfma, dim3(64, 2, SCH), dim3(TPB), 0, stream,
                       img, word, W16sw, lbase, abase, use_slice);

    hipLaunchKernelGGL(finalize_k, dim3((2 * C * D + 255) / 256), dim3(256), 0, stream,
                       lbase, abase, out, use_slice);
}

// Round 8
// 357.713 us; speedup vs baseline: 1.3571x; 1.3571x over previous
//
#include <hip/hip_runtime.h>

using half8   = __attribute__((ext_vector_type(8))) _Float16;
using floatx4 = __attribute__((ext_vector_type(4))) float;

namespace {
constexpr int S = 196, D = 512, C = 1006, Cpad = 1024;
constexpr int CB = 16;      // block c-tile
constexpr int EBLK = 256;   // block e-tile (x2 tanh duplication)
constexpr int BK = 64;      // k-chunk (8 chunks, 2 MFMA k-steps each)
constexpr int TPB = 256;    // 4 waves; 3 blocks/CU (reg-limited: ~100 VGPR + 64 AGPR)
constexpr int SCH = 3;      // s-chunks 66/66/64 -> grid 768 = 3 blocks/CU
constexpr int RS = 64;      // LDS row stride (halfs); banks via XOR swizzle
constexpr float KTANH = 2.885390082f;    // 2/ln2 folded into img staging
constexpr float INVK  = 0.34657359028f;  // ln2/2 to recover raw img
constexpr float LOG2E = 1.44269504f;     // folded into W at prep: acc = log2e*feat

// ws layout (bytes)
constexpr size_t W16_BYTES = (size_t)D * D * 2;               // 512 KB swizzled W
constexpr size_t LA_OFF    = W16_BYTES;
constexpr size_t SLICE_ELEMS = (size_t)2 * Cpad * D;
constexpr size_t SL_BYTES  = (size_t)SCH * SLICE_ELEMS * 4;   // 12 MB per set
constexpr size_t SLICE_NEED = LA_OFF + 2 * SL_BYTES;          // ~24.5 MB (fits; r4 ran slice)
constexpr size_t L_BYTES   = SLICE_ELEMS * 4;

// swizzled LDS offset (halfs): row stride 64, 16B-seg XOR'd by row&7
// (conflict-free on b128 frag reads — SQ_LDS_BANK_CONFLICT==0 in r3/r4)
__device__ __forceinline__ int sw_off(int row, int seg) {
    return row * RS + ((seg ^ (row & 7)) << 3);
}

__device__ __forceinline__ void gload16(const _Float16* g, _Float16* l) {
    // async global->LDS, 16B/lane; LDS dest = wave-uniform base + lane*16
    __builtin_amdgcn_global_load_lds(
        (const __attribute__((address_space(1))) unsigned int*)g,
        (__attribute__((address_space(3))) unsigned int*)l, 16, 0, 0);
}

__device__ __forceinline__ _Float16 tanh_ps(float y) {
    // y = (2/ln2)*x; tanh(x) = 1 - 2/(exp2(y)+1); saturates correctly
    float e = __builtin_amdgcn_exp2f(y);
    return (_Float16)(1.0f - 2.0f * __builtin_amdgcn_rcpf(e + 1.0f));
}

// Pre-swizzle fc3_w*log2e into the exact per-chunk LDS image
// (8 chunks of 512 rows x 8 16B-segs, seg XOR row&7) — same image the kernel DMAs.
__global__ void prep_w16sw(const float* __restrict__ fw, _Float16* __restrict__ W16sw) {
    int id = blockIdx.x * blockDim.x + threadIdx.x;    // 32768 segs
    int kki = id >> 12;
    int r   = (id >> 3) & 511;
    int j   = id & 7;
    const float* src = fw + (size_t)r * D + kki * BK + j * 8;
    floatx4 v0 = *(const floatx4*)src;
    floatx4 v1 = *(const floatx4*)(src + 4);
    half8 h;
    h[0] = (_Float16)(v0[0] * LOG2E); h[1] = (_Float16)(v0[1] * LOG2E);
    h[2] = (_Float16)(v0[2] * LOG2E); h[3] = (_Float16)(v0[3] * LOG2E);
    h[4] = (_Float16)(v1[0] * LOG2E); h[5] = (_Float16)(v1[1] * LOG2E);
    h[6] = (_Float16)(v1[2] * LOG2E); h[7] = (_Float16)(v1[3] * LOG2E);
    *(half8*)&W16sw[((size_t)kki << 15) + r * RS + ((j ^ (r & 7)) << 3)] = h;
}

__global__ __launch_bounds__(TPB, 3) void semdec_mfma(
    const float* __restrict__ img, const float* __restrict__ word,
    const _Float16* __restrict__ W16sw,
    float* __restrict__ lbase, float* __restrict__ abase, int use_slice)
{
    __shared__ __align__(16) _Float16 Wc[EBLK * RS];   // 32 KB
    __shared__ __align__(16) _Float16 Tc[4 * CB * RS]; // 8 KB (4 s x 16 c x 64 k)
    __shared__ __align__(16) float imgS[4][D];         // 8 KB, pre-scaled by 2/ln2
    // total 48 KB -> 3 blocks/CU

    const int ct = blockIdx.x;           // 0..63
    const int et = blockIdx.y & 1;       // 0..1
    const int b  = blockIdx.y >> 1;      // 0..1
    const int sc = blockIdx.z;           // 0..2

    const int tid  = threadIdx.x;
    const int lane = tid & 63;
    const int wv   = tid >> 6;           // wave 0..3 = 64-wide e-slot
    const int l15  = lane & 15;
    const int quad = lane >> 4;

    const int c0 = ct * CB;
    const int e0 = et * EBLK;

    // T-stage mapping (r4): thread -> fixed (ciT, segT); si = it*2 + siB
    const int siB  = tid >> 7;           // 0..1
    const int ciT  = (tid & 127) >> 3;   // 0..15
    const int segT = tid & 7;            // 0..7
    int cgT = c0 + ciT; if (cgT > C - 1) cgT = C - 1;   // clamp pad rows
    const float* wordRowT = word + (size_t)cgT * D + segT * 8;

    floatx4 lacc[4], aacc[4];            // 32 VGPR softmax sums
    #pragma unroll
    for (int ej = 0; ej < 4; ++ej) {
        lacc[ej] = (floatx4){0.f, 0.f, 0.f, 0.f};
        aacc[ej] = (floatx4){0.f, 0.f, 0.f, 0.f};
    }

    const float* imgB = img + (size_t)b * S * D;
    const int s_base = sc * 66;                       // 0, 66, 132
    const int npass = (sc < 2) ? 17 : 16;             // 16x4s (+1x2s for sc<2)

    // word values for chunk 0 (addresses depend only on kk -> cyclic prefetch)
    floatx4 wc0 = *(const floatx4*)(wordRowT);
    floatx4 wc1 = *(const floatx4*)(wordRowT + 4);

    for (int pr = 0; pr < npass; ++pr) {
        const int s0 = s_base + pr * 4;
        const int slim = (pr == 16) ? 2 : 4;          // tail pass covers 2 s

        __syncthreads();  // prior pass readers of imgS/Tc/Wc done
        #pragma unroll
        for (int it = 0; it < 2; ++it) {
            int sid = it * TPB + tid;
            int si = sid >> 7, pos = (sid & 127) << 2;
            floatx4 v = *(const floatx4*)&imgB[(size_t)(s0 + si) * D + pos];
            floatx4 sv = {v[0] * KTANH, v[1] * KTANH, v[2] * KTANH, v[3] * KTANH};
            *(floatx4*)&imgS[si][pos] = sv;
        }

        floatx4 acc[4][4];   // [si][ej] 64 AGPR
        #pragma unroll
        for (int si = 0; si < 4; ++si)
            #pragma unroll
            for (int ej = 0; ej < 4; ++ej)
                acc[si][ej] = (floatx4){0.f, 0.f, 0.f, 0.f};

        for (int kk = 0; kk < D; kk += BK) {
            const int kki = kk >> 6;
            __syncthreads();  // prev chunk frag readers done / imgS staged (kk=0)
            // --- W chunk: async DMA of pre-swizzled image, 8 x 1KB per wave
            {
                const _Float16* wg = W16sw + ((size_t)kki << 15) + ((size_t)e0 << 6);
                #pragma unroll
                for (int it = 0; it < 8; ++it) {
                    int o = ((wv * 8 + it) << 9) + (lane << 3);
                    gload16(wg + o, &Wc[o]);
                }
            }
            // --- T chunk: 4s x 16c x 8 segs, one half8 per thread per it
            //     word values (wc0,wc1) were prefetched during previous MFMA
            #pragma unroll
            for (int it = 0; it < 2; ++it) {
                int si = it * 2 + siB;
                const float* ip = &imgS[si][kk + segT * 8];
                floatx4 i0 = *(const floatx4*)ip;
                floatx4 i1 = *(const floatx4*)(ip + 4);
                half8 t;
                t[0] = tanh_ps(i0[0] * wc0[0]); t[1] = tanh_ps(i0[1] * wc0[1]);
                t[2] = tanh_ps(i0[2] * wc0[2]); t[3] = tanh_ps(i0[3] * wc0[3]);
                t[4] = tanh_ps(i1[0] * wc1[0]); t[5] = tanh_ps(i1[1] * wc1[1]);
                t[6] = tanh_ps(i1[2] * wc1[2]); t[7] = tanh_ps(i1[3] * wc1[3]);
                *(half8*)&Tc[sw_off(si * CB + ciT, segT)] = t;
            }
            __syncthreads();  // drains vmcnt (async W) + lgkm (T writes)

            // --- prefetch next chunk's word values (cyclic: kk=7 -> chunk 0 of
            //     next pass, same address). Issued before MFMA so ~300+ cyc of
            //     MFMA covers the L2 latency; drained at next barrier1.
            const int knext = (kk + BK) & (D - 1);
            floatx4 wn0 = *(const floatx4*)(wordRowT + knext);
            floatx4 wn1 = *(const floatx4*)(wordRowT + knext + 4);

            // --- MFMA: 2 k-steps of 32; 8 frag reads -> 16 MFMA
            #pragma unroll
            for (int k2 = 0; k2 < 2; ++k2) {
                const int jb = (k2 << 2) + quad;
                half8 bf[4], af[4];
                #pragma unroll
                for (int ej = 0; ej < 4; ++ej)
                    bf[ej] = *(const half8*)&Wc[sw_off(wv * 64 + ej * 16 + l15, jb)];
                #pragma unroll
                for (int si = 0; si < 4; ++si)
                    af[si] = *(const half8*)&Tc[sw_off(si * CB + l15, jb)];
                #pragma unroll
                for (int si = 0; si < 4; ++si)
                    #pragma unroll
                    for (int ej = 0; ej < 4; ++ej)
                        acc[si][ej] = __builtin_amdgcn_mfma_f32_16x16x32_f16(
                            af[si], bf[ej], acc[si][ej], 0, 0, 0);
            }
            wc0 = wn0; wc1 = wn1;
        }
        // --- online softmax accumulate; acc = log2e*feat so exp2(acc) = exp(feat)
        #pragma unroll
        for (int si = 0; si < 4; ++si) {
            if (si >= slim) break;
            #pragma unroll
            for (int ej = 0; ej < 4; ++ej) {
                float ie = imgS[si][e0 + wv * 64 + ej * 16 + l15] * INVK;
                #pragma unroll
                for (int r = 0; r < 4; ++r) {
                    float ev = __builtin_amdgcn_exp2f(acc[si][ej][r]);
                    lacc[ej][r] += ev;
                    aacc[ej][r] += ie * ev;
                }
            }
        }
    }

    // --- writeout (C/D layout: col=lane&15 -> e, row=quad*4+r -> c)
    if (use_slice) {
        float* lsl = lbase + (size_t)sc * SLICE_ELEMS;
        float* asl = abase + (size_t)sc * SLICE_ELEMS;
        #pragma unroll
        for (int r = 0; r < 4; ++r) {
            int cg = c0 + quad * 4 + r;
            #pragma unroll
            for (int ej = 0; ej < 4; ++ej) {
                int eg = e0 + wv * 64 + ej * 16 + l15;
                size_t o = ((size_t)b * Cpad + cg) * D + eg;
                lsl[o] = lacc[ej][r];
                asl[o] = aacc[ej][r];
            }
        }
    } else {
        #pragma unroll
        for (int r = 0; r < 4; ++r) {
            int cg = c0 + quad * 4 + r;
            #pragma unroll
            for (int ej = 0; ej < 4; ++ej) {
                int eg = e0 + wv * 64 + ej * 16 + l15;
                atomicAdd(&lbase[((size_t)b * Cpad + cg) * D + eg], lacc[ej][r]);
                if (cg < C)
                    atomicAdd(&abase[((size_t)b * C + cg) * D + eg], aacc[ej][r]);
            }
        }
    }
}

__global__ void finalize_k(const float* __restrict__ lbase, const float* __restrict__ abase,
                           float* __restrict__ out, int use_slice) {
    int o = blockIdx.x * blockDim.x + threadIdx.x;
    if (o >= 2 * C * D) return;
    int b = o / (C * D);
    int rem = o - b * (C * D);
    int c = rem >> 9;
    int e = rem & (D - 1);
    size_t p = ((size_t)b * Cpad + c) * D + e;
    if (use_slice) {
        float l = 0.f, a = 0.f;
        #pragma unroll
        for (int scn = 0; scn < SCH; ++scn) {
            l += lbase[(size_t)scn * SLICE_ELEMS + p];
            a += abase[(size_t)scn * SLICE_ELEMS + p];
        }
        out[o] = a / l;
    } else {
        out[o] = out[o] / lbase[p];
    }
}

} // namespace

extern "C" void kernel_launch(void* const* d_in, const int* in_sizes, int n_in,
                              void* d_out, int out_size, void* d_ws, size_t ws_size,
                              hipStream_t stream) {
    const float* img  = (const float*)d_in[0];
    const float* word = (const float*)d_in[1];
    const float* fw   = (const float*)d_in[2];
    // d_in[3] = fc3_b: constant over softmax axis s -> cancels exactly.
    float* out = (float*)d_out;
    char* ws = (char*)d_ws;

    _Float16* W16sw = (_Float16*)ws;
    const int use_slice = (ws_size >= SLICE_NEED) ? 1 : 0;

    hipLaunchKernelGGL(prep_w16sw, dim3(128), dim3(256), 0, stream, fw, W16sw);

    float *lbase, *abase;
    if (use_slice) {
        lbase = (float*)(ws + LA_OFF);
        abase = (float*)(ws + LA_OFF + SL_BYTES);
    } else {
        lbase = (float*)(ws + LA_OFF);
        abase = out;
        hipMemsetAsync(lbase, 0, L_BYTES, stream);
        hipMemsetAsync(out, 0, (size_t)2 * C * D * 4, stream);
    }

    hipLaunchKernelGGL(semdec_mfma, dim3(64, 4, SCH), dim3(TPB), 0, stream,
                       img, word, W16sw, lbase, abase, use_slice);

    hipLaunchKernelGGL(finalize_k, dim3((2 * C * D + 255) / 256), dim3(256), 0, stream,
                       lbase, abase, out, use_slice);
}